// Round 3
// baseline (139.031 us; speedup 1.0000x reference)
//
#include <hip/hip_runtime.h>

#define NIMG 4
#define NCLS 19
#define CCH  32
#define LH   128
#define LW   128
#define HH   512
#define WW   512
#define HWQ  (LH*LW)    // 16384 low-res pixels
#define HWP  (HH*WW)    // 262144 hi-res pixels

// k_field tiling: each block OWNS a disjoint TRxTC low-res region
#define TR 8
#define TC 8
#define NTX (LW/TC)       // 16
#define NTY (LH/TR)       // 16
#define NTILE (NTY*NTX)   // 256 tiles per image -> 1024 blocks total
#define TCELLS (TR*TC)    // 64
#define RW 10             // ring width  (X0-1 .. X0+8)
#define RING 100          // ring cells 10x10 (Y0-1 .. Y0+8)
#define NACC (NCLS*CCH)   // 608

// Bilinear taps for 128 -> 512, half-pixel convention. Edge taps shifted to a
// valid (b, b+1) pair with weights {1,0}/{0,1} (exact dyadic, same math).
__device__ __forceinline__ void taps(int v, int lim, int& i0, float& w0, float& w1) {
    int r = v & 3;
    int b = (v >> 2) + ((r < 2) ? -1 : 0);
    float f = 0.125f + 0.25f * (float)((r + 2) & 3);   // r: 0->.625 1->.875 2->.125 3->.375
    w0 = 1.f - f; w1 = f;
    if (b < 0)           { b = 0;       w0 = 1.f; w1 = 0.f; }
    else if (b >= lim)   { b = lim - 1; w0 = 0.f; w1 = 1.f; }
    i0 = b;
}

// K0: pre-summed Gram planes (over all 32 ch):
//   G[n][0]=<E,E>  G[n][1]=<E(y,x),E(y,x+1)>  G[n][2]=<E(y,x),E(y+1,x)>
//   G[n][3]=<E(y,x),E(y+1,x+1)> + <E(y,x+1),E(y+1,x)>
// Block (0,0) also zeroes the global accumulators (visible to k_field via
// kernel-boundary cache flush).
__global__ __launch_bounds__(256) void k_gram(const float* __restrict__ E,
        float* __restrict__ G, double* __restrict__ AccS, double* __restrict__ AccS2,
        float* __restrict__ AccC, unsigned int* __restrict__ Cnt) {
    int n = blockIdx.y, rp = blockIdx.x;
    int tid = threadIdx.x;
    if (n == 0 && rp == 0) {
        for (int i = tid; i < NIMG * NACC; i += 256) AccS[i] = 0.0;
        if (tid < NIMG * NCLS) { AccS2[tid] = 0.0; AccC[tid] = 0.f; }
        if (tid < NIMG) Cnt[tid] = 0u;
    }
    int x = tid & 127, dy = tid >> 7;
    int y = rp * 2 + dy;
    int yn = (y < LH - 1) ? y + 1 : y;
    int xn = (x < LW - 1) ? x + 1 : x;
    bool fix = ((x & 63) == 63);             // wave edge: shfl_down(1) invalid
    const float* base = E + (size_t)n * CCH * HWQ;
    const float* Ea = base + y * LW + x;
    const float* Eb = base + yn * LW + x;
    const float* Eax = base + y * LW + xn;
    const float* Ebx = base + yn * LW + xn;
    float gs = 0.f, gh = 0.f, gv = 0.f, gda = 0.f;
#pragma unroll 8
    for (int c = 0; c < CCH; c++) {
        float a = Ea[(size_t)c * HWQ];
        float b = Eb[(size_t)c * HWQ];
        float ar = __shfl_down(a, 1);
        float br = __shfl_down(b, 1);
        if (fix) { ar = Eax[(size_t)c * HWQ]; br = Ebx[(size_t)c * HWQ]; }
        gs = fmaf(a, a, gs);
        gh = fmaf(a, ar, gh);
        gv = fmaf(a, b, gv);
        gda = fmaf(a, br, fmaf(ar, b, gda));
    }
    float* Gp = G + (size_t)n * 4 * HWQ + y * LW + x;
    Gp[0] = gs; Gp[HWQ] = gh; Gp[2 * HWQ] = gv; Gp[3 * HWQ] = gda;
}

// K1: ring-stage Gram, quad-row halo pass (A-field + per-pixel S2 via Gram),
// contract, then f64/f32 global-atomic reduction. Last block per image does
// the final intra/inter math and writes out[n].
__global__ __launch_bounds__(256) void k_field(const float* __restrict__ E,
        const int* __restrict__ lab, const float* __restrict__ G,
        double* __restrict__ AccS, double* __restrict__ AccS2,
        float* __restrict__ AccC, unsigned int* __restrict__ Cnt,
        float* __restrict__ out) {
    int tile = blockIdx.x, n = blockIdx.y;
    int ty = tile >> 4, tx = tile & 15;         // NTX=16
    int Y0 = ty * TR, X0 = tx * TC;
    __shared__ float A[TCELLS * NCLS];          // 4864 B [cell][k]
    __shared__ float Gt[4 * RING];              // 1600 B Gs,Gh,Gv,Gda ring
    __shared__ float red[8 * NCLS * 33];        // 20064 B contract partials (+1 pad)
    __shared__ float S2w[4 * NCLS];             // per-wave S2 accumulators
    __shared__ float tmpc[NCLS * 8];            // cnt partials
    __shared__ unsigned int sdone;
    __shared__ double cs_d[NCLS * 33];
    __shared__ double m_d[NCLS * 33];
    __shared__ double cnt_d[NCLS], s2_d[NCLS];
    __shared__ double wpart[4];
    __shared__ double sIntra, sNfg;
    int tid = threadIdx.x;

    for (int i = tid; i < TCELLS * NCLS; i += 256) A[i] = 0.f;
    if (tid < 4 * NCLS) S2w[tid] = 0.f;
    const float* Gn = G + (size_t)n * 4 * HWQ;
    for (int i = tid; i < 4 * RING; i += 256) {
        int p = i / RING, r = i - p * RING;
        int gy = r / RW, gx = r - gy * RW;
        int yy = Y0 - 1 + gy; yy = yy < 0 ? 0 : (yy > LH - 1 ? LH - 1 : yy);
        int xx = X0 - 1 + gx; xx = xx < 0 ? 0 : (xx > LW - 1 ? LW - 1 : xx);
        Gt[i] = Gn[(size_t)p * HWQ + yy * LW + xx];
    }
    __syncthreads();

    // ---- halo pass: one thread per 4-pixel quad-row ----
    const float* Gs_ = Gt, *Gh_ = Gt + RING, *Gv_ = Gt + 2 * RING, *Gda_ = Gt + 3 * RING;
    const int* ln = lab + (size_t)n * HWP;
    int h_lo = Y0 * 4 - 2;
    for (int i = tid; i < 36 * RW; i += 256) {
        int hr = i / RW, qi = i - hr * RW;
        int h = h_lo + hr;
        int q = X0 - 1 + qi;                 // quad column (4 hi-res pixels)
        if (h < 0 || h >= HH || q < 0 || q >= LW) continue;
        int y0; float wy0, wy1;
        taps(h, LH - 1, y0, wy0, wy1);
        int ry = y0 - Y0;
        bool r0 = (unsigned)ry < (unsigned)TR, r1 = (unsigned)(ry + 1) < (unsigned)TR;
        int rxm = q - 1 - X0, rx0 = q - X0, rxp = q + 1 - X0;
        bool bm = (unsigned)rxm < (unsigned)TC, b0 = (unsigned)rx0 < (unsigned)TC,
             bp = (unsigned)rxp < (unsigned)TC;
        int4 l4 = *(const int4*)(ln + h * WW + (q << 2));
        bool fast = (q >= 1) && (q <= 126);
        bool owned = ((unsigned)(h - Y0 * 4) < 32u) && b0;

        if (fast) {
            // x-weights fixed: p0:(q-1:.375,q:.625) p1:(.125,.875) p2:(q:.875,q+1:.125) p3:(.625,.375)
            if (r0) {
                int rb = (ry * TC) * NCLS;
                if (bm) { float* a = &A[rb + rxm * NCLS];
                    atomicAdd(a + l4.x, wy0 * 0.375f); atomicAdd(a + l4.y, wy0 * 0.125f); }
                if (b0) { float* a = &A[rb + rx0 * NCLS];
                    atomicAdd(a + l4.x, wy0 * 0.625f); atomicAdd(a + l4.y, wy0 * 0.875f);
                    atomicAdd(a + l4.z, wy0 * 0.875f); atomicAdd(a + l4.w, wy0 * 0.625f); }
                if (bp) { float* a = &A[rb + rxp * NCLS];
                    atomicAdd(a + l4.z, wy0 * 0.125f); atomicAdd(a + l4.w, wy0 * 0.375f); }
            }
            if (r1) {
                int rb = ((ry + 1) * TC) * NCLS;
                if (bm) { float* a = &A[rb + rxm * NCLS];
                    atomicAdd(a + l4.x, wy1 * 0.375f); atomicAdd(a + l4.y, wy1 * 0.125f); }
                if (b0) { float* a = &A[rb + rx0 * NCLS];
                    atomicAdd(a + l4.x, wy1 * 0.625f); atomicAdd(a + l4.y, wy1 * 0.875f);
                    atomicAdd(a + l4.z, wy1 * 0.875f); atomicAdd(a + l4.w, wy1 * 0.625f); }
                if (bp) { float* a = &A[rb + rxp * NCLS];
                    atomicAdd(a + l4.z, wy1 * 0.125f); atomicAdd(a + l4.w, wy1 * 0.375f); }
            }
            if (owned) {
                float u0 = wy0 * wy0, u1 = wy1 * wy1, u2t = 2.f * wy0 * wy1;
                int g00 = (y0 - Y0 + 1) * RW + rx0;      // ring idx of cell x=q-1
                float C0 = u0 * Gs_[g00]     + u1 * Gs_[g00 + RW]     + u2t * Gv_[g00];
                float C1 = u0 * Gs_[g00 + 1] + u1 * Gs_[g00 + RW + 1] + u2t * Gv_[g00 + 1];
                float C2 = u0 * Gs_[g00 + 2] + u1 * Gs_[g00 + RW + 2] + u2t * Gv_[g00 + 2];
                float D0 = 2.f * (u0 * Gh_[g00]     + u1 * Gh_[g00 + RW])     + u2t * Gda_[g00];
                float D1 = 2.f * (u0 * Gh_[g00 + 1] + u1 * Gh_[g00 + RW + 1]) + u2t * Gda_[g00 + 1];
                float d2a = fmaf(0.140625f, C0, fmaf(0.390625f, C1, 0.46875f * D0));
                float d2b = fmaf(0.015625f, C0, fmaf(0.765625f, C1, 0.21875f * D0));
                float d2c = fmaf(0.765625f, C1, fmaf(0.015625f, C2, 0.21875f * D1));
                float d2d = fmaf(0.390625f, C1, fmaf(0.140625f, C2, 0.46875f * D1));
                int wv = (tid >> 6) * NCLS;
                atomicAdd(&S2w[wv + l4.x], d2a); atomicAdd(&S2w[wv + l4.y], d2b);
                atomicAdd(&S2w[wv + l4.z], d2c); atomicAdd(&S2w[wv + l4.w], d2d);
            }
        } else {
            // image-border quads: per-pixel taps (clamp-shifted weights)
            int Ls[4] = {l4.x, l4.y, l4.z, l4.w};
            float u0 = wy0 * wy0, u1 = wy1 * wy1, u2t = 2.f * wy0 * wy1;
            int gyr = y0 - Y0 + 1;
            int wv = (tid >> 6) * NCLS;
#pragma unroll
            for (int j = 0; j < 4; j++) {
                int w = (q << 2) + j;
                int x0; float wx0, wx1;
                taps(w, LW - 1, x0, wx0, wx1);
                int rxa = x0 - X0, rxb = rxa + 1;
                int L = Ls[j];
                if (r0) {
                    int rb = (ry * TC) * NCLS;
                    if ((unsigned)rxa < (unsigned)TC) atomicAdd(&A[rb + rxa * NCLS + L], wy0 * wx0);
                    if ((unsigned)rxb < (unsigned)TC) atomicAdd(&A[rb + rxb * NCLS + L], wy0 * wx1);
                }
                if (r1) {
                    int rb = ((ry + 1) * TC) * NCLS;
                    if ((unsigned)rxa < (unsigned)TC) atomicAdd(&A[rb + rxa * NCLS + L], wy1 * wx0);
                    if ((unsigned)rxb < (unsigned)TC) atomicAdd(&A[rb + rxb * NCLS + L], wy1 * wx1);
                }
                if (owned) {
                    int gg = gyr * RW + (x0 - X0 + 1);
                    float Ca = u0 * Gs_[gg]     + u1 * Gs_[gg + RW]     + u2t * Gv_[gg];
                    float Cb = u0 * Gs_[gg + 1] + u1 * Gs_[gg + RW + 1] + u2t * Gv_[gg + 1];
                    float Dd = 2.f * (u0 * Gh_[gg] + u1 * Gh_[gg + RW]) + u2t * Gda_[gg];
                    float d2 = wx0 * wx0 * Ca + wx1 * wx1 * Cb + 2.f * wx0 * wx1 * Dd;
                    atomicAdd(&S2w[wv + L], d2);
                }
            }
        }
    }
    __syncthreads();

    // ---- contract: thread (c = tid>>3, cy = tid&7), E as 2x float4 ----
    {
        int c = tid >> 3, cy = tid & 7;
        const float* Er = E + ((size_t)n * CCH + c) * HWQ + (Y0 + cy) * LW + X0;
        float4 v0 = *(const float4*)Er;
        float4 v1 = *(const float4*)(Er + 4);
        float ev[8] = {v0.x, v0.y, v0.z, v0.w, v1.x, v1.y, v1.z, v1.w};
        float acc[NCLS];
#pragma unroll
        for (int k = 0; k < NCLS; k++) acc[k] = 0.f;
#pragma unroll
        for (int cx = 0; cx < 8; cx++) {
            const float* Ar = &A[(cy * 8 + cx) * NCLS];
            float e = ev[cx];
#pragma unroll
            for (int k = 0; k < NCLS; k++) acc[k] = fmaf(Ar[k], e, acc[k]);
        }
#pragma unroll
        for (int k = 0; k < NCLS; k++) red[(cy * NCLS + k) * 33 + c] = acc[k];
    }
    if (tid < 8 * NCLS) {                     // cnt partials: 8 groups x 19 classes
        int g8 = tid / NCLS, k = tid - g8 * NCLS;
        float s = 0.f;
#pragma unroll
        for (int j = 0; j < 8; j++) s += A[(g8 * 8 + j) * NCLS + k];
        tmpc[k * 8 + g8] = s;
    }
    __syncthreads();

    // ---- global accumulate (f64 for sums/S2, exact f32 for counts) ----
    for (int idx = tid; idx < NACC; idx += 256) {
        int k = idx >> 5, c = idx & 31;
        float s = 0.f;
#pragma unroll
        for (int gg = 0; gg < 8; gg++) s += red[(gg * NCLS + k) * 33 + c];
        atomicAdd(&AccS[n * NACC + idx], (double)s);
    }
    if (tid < NCLS) {
        float s = 0.f;
#pragma unroll
        for (int g8 = 0; g8 < 8; g8++) s += tmpc[tid * 8 + g8];
        atomicAdd(&AccC[n * NCLS + tid], s);
        float s2 = S2w[tid] + S2w[NCLS + tid] + S2w[2 * NCLS + tid] + S2w[3 * NCLS + tid];
        atomicAdd(&AccS2[n * NCLS + tid], (double)s2);
    }
    __syncthreads();
    if (tid == 0) { __threadfence(); sdone = atomicAdd(&Cnt[n], 1u); }
    __syncthreads();
    if (sdone != NTILE - 1) return;

    // ---- last block of image n: final math ----
    __threadfence();
    for (int idx = tid; idx < NACC; idx += 256)
        cs_d[(idx >> 5) * 33 + (idx & 31)] = atomicAdd(&AccS[n * NACC + idx], 0.0);
    if (tid < NCLS) {
        cnt_d[tid] = (double)atomicAdd(&AccC[n * NCLS + tid], 0.f);
        s2_d[tid]  = atomicAdd(&AccS2[n * NCLS + tid], 0.0);
    }
    __syncthreads();
    for (int idx = tid; idx < NACC; idx += 256) {
        int k = idx >> 5, c = idx & 31;
        m_d[k * 33 + c] = cs_d[k * 33 + c] / (cnt_d[k] + 1.0);
    }
    __syncthreads();
    double vi = 0.0, fg = 0.0;
    if (tid >= 1 && tid < NCLS && cnt_d[tid] > 0.0) {
        fg = 1.0;
        double dot = 0.0, mm = 0.0;
        for (int c = 0; c < CCH; c++) {
            double mv = m_d[tid * 33 + c];
            dot += mv * cs_d[tid * 33 + c];
            mm += mv * mv;
        }
        vi = (s2_d[tid] - 2.0 * dot + cnt_d[tid] * mm) * 0.03125 / (cnt_d[tid] + 1.0);
    }
    if (tid < 64) {
#pragma unroll
        for (int s_ = 32; s_ >= 1; s_ >>= 1) { vi += __shfl_xor(vi, s_); fg += __shfl_xor(fg, s_); }
        if (tid == 0) { sIntra = vi; sNfg = fg; }
    }
    double ve = 0.0;
    for (int t2 = tid; t2 < 324; t2 += 256) {
        int j = 1 + t2 / 18, k = 1 + t2 % 18;
        if (cnt_d[j] > 0.0 && cnt_d[k] > 0.0) {
            double s = 0.0;
            for (int c = 0; c < CCH; c++) {
                double d = m_d[j * 33 + c] - m_d[k * 33 + c];
                s += d * d;
            }
            ve += s * 0.03125;
        }
    }
#pragma unroll
    for (int s_ = 32; s_ >= 1; s_ >>= 1) ve += __shfl_xor(ve, s_);
    if ((tid & 63) == 0) wpart[tid >> 6] = ve;
    __syncthreads();
    if (tid == 0) {
        double inter = wpart[0] + wpart[1] + wpart[2] + wpart[3];
        out[n] = (float)(sIntra / sNfg - inter / (sNfg * sNfg));
    }
}

extern "C" void kernel_launch(void* const* d_in, const int* in_sizes, int n_in,
                              void* d_out, int out_size, void* d_ws, size_t ws_size,
                              hipStream_t stream) {
    const float* E = (const float*)d_in[0];   // (4,32,128,128) fp32
    const int* lab = (const int*)d_in[1];     // (4,512,512) int
    float* out = (float*)d_out;               // (4,) fp32

    double* AccS  = (double*)d_ws;                       // NIMG*608 doubles
    double* AccS2 = AccS + (size_t)NIMG * NACC;          // NIMG*19 doubles
    float*  AccC  = (float*)(AccS2 + NIMG * NCLS);       // NIMG*19 floats
    unsigned int* Cnt = (unsigned int*)(AccC + NIMG * NCLS); // NIMG counters
    float*  G     = (float*)(Cnt + NIMG);                // NIMG*4*HWQ floats (1 MB)
    // accumulators are zeroed by k_gram block (0,0) each call

    k_gram <<<dim3(64, NIMG),    dim3(256), 0, stream>>>(E, G, AccS, AccS2, AccC, Cnt);
    k_field<<<dim3(NTILE, NIMG), dim3(256), 0, stream>>>(E, lab, G, AccS, AccS2, AccC, Cnt, out);
}